// Round 1
// baseline (11864.670 us; speedup 1.0000x reference)
//
#include <hip/hip_runtime.h>
#include <hip/hip_bf16.h>
#include <math.h>

#define D 768
#define T_CTX 1024
#define NH 6
#define HS 128
#define FFD 3072
#define NL 6
#define VOCAB 32000
#define ROWS 4096   // B*T

// ---------------- embedding: x[b,t,:] = tok_emb[idx[b,t]] + pos_emb[t] ----
__global__ __launch_bounds__(192) void embed_kernel(
    const int* __restrict__ idx, const float* __restrict__ tok,
    const float* __restrict__ pos, float* __restrict__ x)
{
    int row = blockIdx.x;           // b*T + t
    int t = row & (T_CTX - 1);
    int tk = idx[row];
    const float4* t4 = (const float4*)(tok + (long)tk * D);
    const float4* p4 = (const float4*)(pos + (long)t * D);
    float4* x4 = (float4*)(x + (long)row * D);
    int c = threadIdx.x;            // 0..191  (768/4)
    float4 a = t4[c], b = p4[c];
    x4[c] = make_float4(a.x + b.x, a.y + b.y, a.z + b.z, a.w + b.w);
}

// ---------------- layernorm (row of 768) ---------------------------------
__global__ __launch_bounds__(256) void ln_kernel(
    const float* __restrict__ x, const float* __restrict__ g,
    const float* __restrict__ b, float* __restrict__ out)
{
    int row = blockIdx.x;
    const float* xr = x + (long)row * D;
    int tid = threadIdx.x;
    float v0 = xr[tid], v1 = xr[tid + 256], v2 = xr[tid + 512];
    float s  = v0 + v1 + v2;
    float s2 = v0 * v0 + v1 * v1 + v2 * v2;
    #pragma unroll
    for (int off = 32; off >= 1; off >>= 1) {
        s  += __shfl_xor(s, off);
        s2 += __shfl_xor(s2, off);
    }
    __shared__ float ws_[4], ws2_[4];
    int wid = tid >> 6, lane = tid & 63;
    if (lane == 0) { ws_[wid] = s; ws2_[wid] = s2; }
    __syncthreads();
    s  = ws_[0] + ws_[1] + ws_[2] + ws_[3];
    s2 = ws2_[0] + ws2_[1] + ws2_[2] + ws2_[3];
    float mu  = s * (1.0f / D);
    float var = s2 * (1.0f / D) - mu * mu;
    float rs  = rsqrtf(var + 1e-5f);
    float* orow = out + (long)row * D;
    orow[tid]       = (v0 - mu) * rs * g[tid]       + b[tid];
    orow[tid + 256] = (v1 - mu) * rs * g[tid + 256] + b[tid + 256];
    orow[tid + 512] = (v2 - mu) * rs * g[tid + 512] + b[tid + 512];
}

// ---------------- generic fp32 GEMM: C = A*B (+bias)(+res)(relu) ---------
// A: [M,K] row-major lda. B: [K,N] row-major ldb, per-z offset b_zstride.
// C columns offset by z*c_zoff (QKV heads). All dims multiples of tile.
// 64x64 tile, BK=16, 256 threads, 4x4 microtile.
__global__ __launch_bounds__(256) void gemm_kernel(
    const float* __restrict__ A, int lda,
    const float* __restrict__ Bm, int ldb, long b_zstride,
    float* __restrict__ C, int ldc, int c_zoff,
    const float* __restrict__ bias, const float* __restrict__ res,
    int K, int relu)
{
    const float* B = Bm + (long)blockIdx.z * b_zstride;
    int bm = blockIdx.y * 64;
    int bn = blockIdx.x * 64;
    int zoff = blockIdx.z * c_zoff;
    __shared__ float As[16][68];   // [k][m], +4 pad
    __shared__ float Bs[16][68];   // [k][n], +4 pad
    int tid = threadIdx.x;
    int tx = tid & 15, ty = tid >> 4;
    int arow = tid >> 2, akq = (tid & 3) << 2;
    int bkrow = tid >> 4, bnq = (tid & 15) << 2;
    float acc[4][4] = {{0.f, 0.f, 0.f, 0.f}};
    const float* Aptr = A + (long)(bm + arow) * lda + akq;
    const float* Bptr = B + (long)bkrow * ldb + bn + bnq;
    for (int k0 = 0; k0 < K; k0 += 16) {
        float4 a4 = *(const float4*)(Aptr + k0);
        float4 b4 = *(const float4*)(Bptr + (long)k0 * ldb);
        As[akq + 0][arow] = a4.x;
        As[akq + 1][arow] = a4.y;
        As[akq + 2][arow] = a4.z;
        As[akq + 3][arow] = a4.w;
        *(float4*)&Bs[bkrow][bnq] = b4;
        __syncthreads();
        #pragma unroll
        for (int kk = 0; kk < 16; ++kk) {
            float4 av = *(const float4*)&As[kk][ty << 2];
            float4 bv = *(const float4*)&Bs[kk][tx << 2];
            acc[0][0] = fmaf(av.x, bv.x, acc[0][0]);
            acc[0][1] = fmaf(av.x, bv.y, acc[0][1]);
            acc[0][2] = fmaf(av.x, bv.z, acc[0][2]);
            acc[0][3] = fmaf(av.x, bv.w, acc[0][3]);
            acc[1][0] = fmaf(av.y, bv.x, acc[1][0]);
            acc[1][1] = fmaf(av.y, bv.y, acc[1][1]);
            acc[1][2] = fmaf(av.y, bv.z, acc[1][2]);
            acc[1][3] = fmaf(av.y, bv.w, acc[1][3]);
            acc[2][0] = fmaf(av.z, bv.x, acc[2][0]);
            acc[2][1] = fmaf(av.z, bv.y, acc[2][1]);
            acc[2][2] = fmaf(av.z, bv.z, acc[2][2]);
            acc[2][3] = fmaf(av.z, bv.w, acc[2][3]);
            acc[3][0] = fmaf(av.w, bv.x, acc[3][0]);
            acc[3][1] = fmaf(av.w, bv.y, acc[3][1]);
            acc[3][2] = fmaf(av.w, bv.z, acc[3][2]);
            acc[3][3] = fmaf(av.w, bv.w, acc[3][3]);
        }
        __syncthreads();
    }
    #pragma unroll
    for (int i = 0; i < 4; ++i) {
        int mrow = bm + (ty << 2) + i;
        #pragma unroll
        for (int j = 0; j < 4; ++j) {
            int col = zoff + bn + (tx << 2) + j;
            long ci = (long)mrow * ldc + col;
            float vv = acc[i][j];
            if (bias) vv += bias[col];
            if (res)  vv += res[ci];
            if (relu) vv = fmaxf(vv, 0.f);
            C[ci] = vv;
        }
    }
}

// ---------------- flash attention --------------------------------------
// q,k,v layout: [B*T, D] with column = h*HS + e (head-major). One wave per
// query row, 4 rows per block. K/V tiles (64 rows) staged in LDS.
__global__ __launch_bounds__(256) void attn_kernel(
    const float* __restrict__ q, const float* __restrict__ k,
    const float* __restrict__ v, float* __restrict__ att)
{
    int bh = blockIdx.z;             // b*NH + h
    int b = bh / NH, hh = bh % NH;
    int t0 = blockIdx.x * 4;
    int tid = threadIdx.x;
    int w = tid >> 6, lane = tid & 63;
    int t = t0 + w;
    const float* qb = q + (long)b * T_CTX * D + hh * HS;
    const float* kb = k + (long)b * T_CTX * D + hh * HS;
    const float* vb = v + (long)b * T_CTX * D + hh * HS;
    __shared__ float Qs[4][HS];        // 2 KB
    __shared__ float Ks[64][HS + 1];   // 33 KB, pad -> 2-way (free) column reads
    __shared__ float Vs[64][HS];       // 32 KB
    __shared__ float Ps[4][64];        // 1 KB
    for (int i = tid; i < 4 * HS; i += 256) {
        int r = i >> 7, c = i & 127;
        Qs[r][c] = qb[(long)(t0 + r) * D + c];
    }
    float m = -1e30f, l = 0.f, o0 = 0.f, o1 = 0.f;
    const float scale = 0.0883883476483184f;  // 1/sqrt(128)
    int ntiles = (t0 + 3) / 64 + 1;
    for (int tile = 0; tile < ntiles; ++tile) {
        int kt0 = tile * 64;
        __syncthreads();
        for (int i = tid; i < 64 * 32; i += 256) {
            int r = i >> 5, cq = (i & 31) << 2;
            float4 kv = *(const float4*)(kb + (long)(kt0 + r) * D + cq);
            Ks[r][cq + 0] = kv.x; Ks[r][cq + 1] = kv.y;
            Ks[r][cq + 2] = kv.z; Ks[r][cq + 3] = kv.w;
            *(float4*)&Vs[r][cq] = *(const float4*)(vb + (long)(kt0 + r) * D + cq);
        }
        __syncthreads();
        if (kt0 <= t) {
            int s = kt0 + lane;
            float dot = 0.f;
            #pragma unroll
            for (int c = 0; c < HS; ++c) dot = fmaf(Qs[w][c], Ks[lane][c], dot);
            float sc = (s <= t) ? dot * scale : -1e30f;
            float mt = sc;
            #pragma unroll
            for (int off = 32; off >= 1; off >>= 1) mt = fmaxf(mt, __shfl_xor(mt, off));
            float mnew = fmaxf(m, mt);
            float p = (s <= t) ? __expf(sc - mnew) : 0.f;
            float ls = p;
            #pragma unroll
            for (int off = 32; off >= 1; off >>= 1) ls += __shfl_xor(ls, off);
            float alpha = __expf(m - mnew);
            l = l * alpha + ls;
            o0 *= alpha; o1 *= alpha;
            m = mnew;
            Ps[w][lane] = p;
            #pragma unroll 8
            for (int ss = 0; ss < 64; ++ss) {
                float pv = Ps[w][ss];
                o0 = fmaf(pv, Vs[ss][lane], o0);
                o1 = fmaf(pv, Vs[ss][lane + 64], o1);
            }
        }
    }
    float inv = 1.0f / l;
    float* ar = att + (long)(b * T_CTX + t) * D + hh * HS;
    ar[lane]      = o0 * inv;
    ar[lane + 64] = o1 * inv;
}

// ---------------- launch -------------------------------------------------
extern "C" void kernel_launch(void* const* d_in, const int* in_sizes, int n_in,
                              void* d_out, int out_size, void* d_ws, size_t ws_size,
                              hipStream_t stream) {
    (void)in_sizes; (void)n_in; (void)out_size; (void)ws_size;
    const int*   idx     = (const int*)  d_in[0];
    const float* tok_emb = (const float*)d_in[1];
    const float* pos_emb = (const float*)d_in[2];
    const float* wq      = (const float*)d_in[3];
    const float* wk      = (const float*)d_in[4];
    const float* wv      = (const float*)d_in[5];
    const float* wo      = (const float*)d_in[6];
    const float* bo      = (const float*)d_in[7];
    const float* w1      = (const float*)d_in[8];
    const float* b1      = (const float*)d_in[9];
    const float* w2      = (const float*)d_in[10];
    const float* b2      = (const float*)d_in[11];
    const float* g1      = (const float*)d_in[12];
    const float* be1     = (const float*)d_in[13];
    const float* g2      = (const float*)d_in[14];
    const float* be2     = (const float*)d_in[15];
    const float* wlm     = (const float*)d_in[16];
    const float* blm     = (const float*)d_in[17];
    float* out = (float*)d_out;

    const long SZ = (long)ROWS * D;     // 3,145,728 floats
    float* ws   = (float*)d_ws;
    float* x    = ws;                   // [4096, 768]
    float* h    = ws + SZ;              // [4096, 768]
    float* q    = ws + 2 * SZ;          // [4096, 768]
    float* kbuf = ws + 3 * SZ;
    float* vbuf = ws + 4 * SZ;
    float* att  = ws + 5 * SZ;
    float* ff   = q;                    // [4096, 3072] reuses q..att (exact fit)

    embed_kernel<<<ROWS, 192, 0, stream>>>(idx, tok_emb, pos_emb, x);

    for (int l = 0; l < NL; ++l) {
        ln_kernel<<<ROWS, 256, 0, stream>>>(x, g1 + l * D, be1 + l * D, h);

        dim3 gq(2, 64, NH);
        const long wsz = (long)NH * D * HS;   // per-layer q/k/v weight size
        gemm_kernel<<<gq, 256, 0, stream>>>(h, D, wq + (long)l * wsz, HS,
                                            (long)D * HS, q, D, HS,
                                            nullptr, nullptr, D, 0);
        gemm_kernel<<<gq, 256, 0, stream>>>(h, D, wk + (long)l * wsz, HS,
                                            (long)D * HS, kbuf, D, HS,
                                            nullptr, nullptr, D, 0);
        gemm_kernel<<<gq, 256, 0, stream>>>(h, D, wv + (long)l * wsz, HS,
                                            (long)D * HS, vbuf, D, HS,
                                            nullptr, nullptr, D, 0);

        attn_kernel<<<dim3(T_CTX / 4, 1, 4 * NH), 256, 0, stream>>>(q, kbuf, vbuf, att);

        // x = x + att @ wo + bo
        gemm_kernel<<<dim3(12, 64, 1), 256, 0, stream>>>(
            att, D, wo + (long)l * D * D, D, 0, x, D, 0,
            bo + l * D, x, D, 0);

        ln_kernel<<<ROWS, 256, 0, stream>>>(x, g2 + l * D, be2 + l * D, h);

        // ff = relu(h @ w1 + b1)
        gemm_kernel<<<dim3(48, 64, 1), 256, 0, stream>>>(
            h, D, w1 + (long)l * D * FFD, FFD, 0, ff, FFD, 0,
            b1 + (long)l * FFD, nullptr, D, 1);

        // x = x + ff @ w2 + b2
        gemm_kernel<<<dim3(12, 64, 1), 256, 0, stream>>>(
            ff, FFD, w2 + (long)l * FFD * D, D, 0, x, D, 0,
            b2 + l * D, x, FFD, 0);
    }

    // out = x @ wlm + blm
    gemm_kernel<<<dim3(VOCAB / 64, 64, 1), 256, 0, stream>>>(
        x, D, wlm, VOCAB, 0, out, VOCAB, 0, blm, nullptr, D, 0);
}